// Round 7
// baseline (151.216 us; speedup 1.0000x reference)
//
#include <hip/hip_runtime.h>
#include <cstddef>

#define N_TOT   8
#define R_TOT   2048
#define NR_TOT  (N_TOT*R_TOT)      // 16384 points
#define KK      16
#define CL      64
#define CM      128
#define EPSV    1e-5f
#define CNTF    262144.0f

typedef float    f32x4  __attribute__((ext_vector_type(4)));
typedef short    bf16x8 __attribute__((ext_vector_type(8)));
typedef unsigned u32x2  __attribute__((ext_vector_type(2)));
typedef unsigned u32x4  __attribute__((ext_vector_type(4)));

union FragU { bf16x8 f; unsigned u[4]; };

__device__ __forceinline__ float elu_f(float x){
    return x > 0.f ? x : (__expf(x) - 1.f);
}

#if defined(__has_builtin) && __has_builtin(__builtin_amdgcn_cvt_pk_bf16_f32)
__device__ __forceinline__ unsigned pk_bf16(float a, float b){
    auto v = __builtin_amdgcn_cvt_pk_bf16_f32(a, b);   // lo=a, hi=b
    unsigned u; __builtin_memcpy(&u, &v, 4);
    return u;
}
#else
__device__ __forceinline__ unsigned pk_bf16(float a, float b){
    unsigned ua = __float_as_uint(a), ub = __float_as_uint(b);
    ua += 0x7fff + ((ua >> 16) & 1);
    ub += 0x7fff + ((ub >> 16) & 1);
    return (ua >> 16) | (ub & 0xffff0000u);
}
#endif
__device__ __forceinline__ float bf_lo(unsigned u){ return __uint_as_float(u << 16); }
__device__ __forceinline__ float bf_hi(unsigned u){ return __uint_as_float(u & 0xffff0000u); }

__device__ __forceinline__ void split4(const float* x, unsigned* o){
    unsigned h01 = pk_bf16(x[0], x[1]);
    unsigned h23 = pk_bf16(x[2], x[3]);
    float l0 = x[0] - bf_lo(h01), l1 = x[1] - bf_hi(h01);
    float l2 = x[2] - bf_lo(h23), l3 = x[3] - bf_hi(h23);
    o[0] = h01; o[1] = h23; o[2] = pk_bf16(l0, l1); o[3] = pk_bf16(l2, l3);
}

// ---------------- Pass 1: global BN stats ----------------
__global__ __launch_bounds__(256) void xconv_stats(
    const float* __restrict__ p, const float* __restrict__ P, float* __restrict__ ws)
{
    const int g = blockIdx.x*256 + threadIdx.x;        // group of 4 neighbor rows
    const float4* P4 = (const float4*)(P + (size_t)g*12);
    float4 a = P4[0], b = P4[1], c = P4[2];
    const int nr = g >> 2;
    float pp0 = p[nr*3], pp1 = p[nr*3+1], pp2 = p[nr*3+2];
    float vx0=a.x-pp0, vx1=a.w-pp0, vx2=b.z-pp0, vx3=c.y-pp0;
    float vy0=a.y-pp1, vy1=b.x-pp1, vy2=b.w-pp1, vy3=c.z-pp1;
    float vz0=a.z-pp2, vz1=b.y-pp2, vz2=c.x-pp2, vz3=c.w-pp2;
    float s1[3], s2[3];
    s1[0]=vx0+vx1+vx2+vx3; s2[0]=vx0*vx0+vx1*vx1+vx2*vx2+vx3*vx3;
    s1[1]=vy0+vy1+vy2+vy3; s2[1]=vy0*vy0+vy1*vy1+vy2*vy2+vy3*vy3;
    s1[2]=vz0+vz1+vz2+vz3; s2[2]=vz0*vz0+vz1*vz1+vz2*vz2+vz3*vz3;

    #pragma unroll
    for (int off = 32; off > 0; off >>= 1){
        #pragma unroll
        for (int d = 0; d < 3; d++){
            s1[d] += __shfl_down(s1[d], off, 64);
            s2[d] += __shfl_down(s2[d], off, 64);
        }
    }
    __shared__ float red[4][6];
    int wave = threadIdx.x >> 6, lane = threadIdx.x & 63;
    if (lane == 0){
        #pragma unroll
        for (int d = 0; d < 3; d++){ red[wave][d] = s1[d]; red[wave][3+d] = s2[d]; }
    }
    __syncthreads();
    if (threadIdx.x < 6){
        float v = red[0][threadIdx.x] + red[1][threadIdx.x]
                + red[2][threadIdx.x] + red[3][threadIdx.x];
        atomicAdd(&ws[threadIdx.x], v);
    }
}

// ---------------- Pass 2: fused MFMA kernel, 2-stage software pipeline ------
// 1024 blocks x 256 thr; wave = 4 points. w1/w2 fragments staged in LDS to
// keep VGPR under the 3-4 waves/SIMD tier with 2 points in flight.
struct PS { FragU hf[2]; FragU xA; float fv[4][4]; int nr; };

__global__ __launch_bounds__(256) void xconv_main(
    const float* __restrict__ p,   const float* __restrict__ P,
    const float* __restrict__ F,
    const float* __restrict__ gamma,const float* __restrict__ beta,
    const float* __restrict__ w1,  const float* __restrict__ b1,
    const float* __restrict__ w2,  const float* __restrict__ b2,
    const float* __restrict__ midw,const float* __restrict__ midb,
    const float* __restrict__ mlpw,const float* __restrict__ mlpb,
    const float* __restrict__ endw,const float* __restrict__ endb,
    const float* __restrict__ ws,  float* __restrict__ out)
{
    __shared__ float    sEndw[128*20];     // 10240 B, rows padded to 80 B
    __shared__ unsigned sW1[2*64*20];      // 10240 B, per-(s,lane) 80 B rows
    __shared__ unsigned sW2[8*64*4];       //  8192 B, per-(b,s,lane) 16 B frags

    const int tid  = threadIdx.x;
    const int lane = tid & 63;
    const int lo16 = lane & 15;
    const int quad = lane >> 4;
    const int wave = tid >> 6;

    // ---- parallel LDS staging: wave0=w1, wave1=w2, waves2-3=endw ----
    if (wave == 0){
        #pragma unroll
        for (int s = 0; s < 2; s++)
            #pragma unroll
            for (int j = 0; j < 8; j++){
                int q = s*32 + quad*8 + j;
                u32x2 v;
                v.x = pk_bf16(w1[q],       w1[64 + q]);   // (w1_0, w1_1)
                v.y = pk_bf16(w1[128 + q], b1[q]);        // (w1_2, bias)
                *(u32x2*)&sW1[(s*64 + lane)*20 + j*2] = v;
            }
    } else if (wave == 1){
        #pragma unroll
        for (int b = 0; b < 4; b++)
            #pragma unroll
            for (int s = 0; s < 2; s++){
                u32x4 f;
                #pragma unroll
                for (int d = 0; d < 4; d++){
                    int q0 = s*32 + quad*8 + d*2;
                    int idx = q0*64 + b*16 + lo16;
                    f[d] = pk_bf16(w2[idx], w2[idx + 64]);
                }
                *(u32x4*)&sW2[((b*2 + s)*64 + lane)*4] = f;
            }
    } else {
        int c = tid - 128;                                // 0..127
        const float4* ep = (const float4*)endw;
        #pragma unroll
        for (int i = 0; i < 4; i++)
            *(float4*)&sEndw[c*20 + i*4] = ep[c*4 + i];
    }

    // ---- per-lane persistent regs (all waves) ----
    float sc[3], sh[3];
    #pragma unroll
    for (int d = 0; d < 3; d++){
        float mean = ws[d] / CNTF;
        float var  = ws[3+d] / CNTF - mean*mean;
        float s    = gamma[d] * rsqrtf(var + EPSV);
        sc[d] = s; sh[d] = beta[d] - mean*s;
    }
    FragU mlpA[2];
    {
        float mw[4];
        #pragma unroll
        for (int r = 0; r < 4; r++) mw[r] = mlpw[(quad*4 + r)*16 + lo16];
        unsigned o[4]; split4(mw, o);
        mlpA[0].u[0]=o[0]; mlpA[0].u[1]=o[1]; mlpA[0].u[2]=o[0]; mlpA[0].u[3]=o[1];
        mlpA[1].u[0]=o[2]; mlpA[1].u[1]=o[3]; mlpA[1].u[2]=o[2]; mlpA[1].u[3]=o[3];
    }
    float mlpbr[4];
    #pragma unroll
    for (int r = 0; r < 4; r++) mlpbr[r] = mlpb[quad*4 + r];
    float mw0[4], mw1[4], mw2[4], mbv[4];
    #pragma unroll
    for (int j = 0; j < 4; j++){
        int m2 = quad*4 + j;
        mw0[j] = midw[m2]; mw1[j] = midw[16 + m2]; mw2[j] = midw[32 + m2];
        mbv[j] = midb[m2];
    }
    float b2r[4];
    #pragma unroll
    for (int b = 0; b < 4; b++) b2r[b] = b2[b*16 + lo16];
    const float endb0 = endb[lane], endb1 = endb[64 + lane];

    __syncthreads();

    // ---- front: loads + lift1 + x-transform -> pipeline state ----
    auto front = [&](int nr, PS& S){
        S.nr = nr;
        #pragma unroll
        for (int bt = 0; bt < 4; bt++)
            #pragma unroll
            for (int r = 0; r < 4; r++)
                S.fv[bt][r] = F[(size_t)nr*1024 + (quad*4 + r)*64 + bt*16 + lo16];

        const int pb = nr*48 + lo16*3;
        float P0 = P[pb], P1 = P[pb+1], P2 = P[pb+2];
        float pp0 = p[nr*3], pp1 = p[nr*3+1], pp2 = p[nr*3+2];
        const float pn0 = (P0 - pp0)*sc[0] + sh[0];
        const float pn1 = (P1 - pp1)*sc[1] + sh[1];
        const float pn2 = (P2 - pp2)*sc[2] + sh[2];

        // h1 = elu(Pn @ w1 + b1) -> A-frags, weights from LDS
        #pragma unroll
        for (int s = 0; s < 2; s++){
            const u32x4* wp = (const u32x4*)&sW1[(s*64 + lane)*20];
            #pragma unroll
            for (int d = 0; d < 4; d++){
                u32x4 w = wp[d];              // pa(2d), pb(2d), pa(2d+1), pb(2d+1)
                float h0 = bf_hi(w.y);
                h0 = fmaf(pn0, bf_lo(w.x), h0);
                h0 = fmaf(pn1, bf_hi(w.x), h0);
                h0 = fmaf(pn2, bf_lo(w.y), h0);
                float h1v = bf_hi(w.w);
                h1v = fmaf(pn0, bf_lo(w.z), h1v);
                h1v = fmaf(pn1, bf_hi(w.z), h1v);
                h1v = fmaf(pn2, bf_lo(w.w), h1v);
                S.hf[s].u[d] = pk_bf16(elu_f(h0), elu_f(h1v));
            }
        }
        // X0 exact fp32 -> split B-frag
        float x0[4];
        #pragma unroll
        for (int j = 0; j < 4; j++)
            x0[j] = fmaf(pn2, mw2[j], fmaf(pn1, mw1[j], fmaf(pn0, mw0[j], mbv[j])));
        FragU x0f; split4(x0, x0f.u);
        // mlp: X^T = mlpw^T @ X0^T (exact), ELU, split -> agg A-frag
        f32x4 dx = {0.f,0.f,0.f,0.f};
        dx = __builtin_amdgcn_mfma_f32_16x16x32_bf16(mlpA[0].f, x0f.f, dx, 0,0,0);
        dx = __builtin_amdgcn_mfma_f32_16x16x32_bf16(mlpA[1].f, x0f.f, dx, 0,0,0);
        float xv[4];
        #pragma unroll
        for (int r = 0; r < 4; r++) xv[r] = elu_f(dx[r] + mlpbr[r]);
        split4(xv, S.xA.u);
    };

    // ---- back: 8 c-tiles + depthwise epilogue + store ----
    auto back = [&](PS& S){
        float o0 = 0.f, o1 = 0.f;
        #pragma unroll
        for (int b = 0; b < 4; b++){
            FragU wf0, wf1;
            *(u32x4*)wf0.u = *(const u32x4*)&sW2[((b*2 + 0)*64 + lane)*4];
            *(u32x4*)wf1.u = *(const u32x4*)&sW2[((b*2 + 1)*64 + lane)*4];
            f32x4 dl = {0.f,0.f,0.f,0.f};
            dl = __builtin_amdgcn_mfma_f32_16x16x32_bf16(S.hf[0].f, wf0.f, dl, 0,0,0);
            dl = __builtin_amdgcn_mfma_f32_16x16x32_bf16(S.hf[1].f, wf1.f, dl, 0,0,0);
            float fl[4];
            #pragma unroll
            for (int r = 0; r < 4; r++) fl[r] = elu_f(dl[r] + b2r[b]);
            FragU bfg;
            unsigned h01 = pk_bf16(fl[0], fl[1]), h23 = pk_bf16(fl[2], fl[3]);
            bfg.u[0] = h01; bfg.u[1] = h23; bfg.u[2] = h01; bfg.u[3] = h23;
            f32x4 da = {0.f,0.f,0.f,0.f};
            da = __builtin_amdgcn_mfma_f32_16x16x32_bf16(S.xA.f, bfg.f, da, 0,0,0);
            const float4 ew = *(const float4*)&sEndw[(b*16 + lo16)*20 + quad*4];
            float pt = da[0]*ew.x + da[1]*ew.y + da[2]*ew.z + da[3]*ew.w;
            pt += __shfl_xor(pt, 16, 64);
            pt += __shfl_xor(pt, 32, 64);
            if (b == quad) o0 = pt;
        }
        #pragma unroll
        for (int bt = 0; bt < 4; bt++){
            FragU bfg;
            unsigned h01 = pk_bf16(S.fv[bt][0], S.fv[bt][1]);
            unsigned h23 = pk_bf16(S.fv[bt][2], S.fv[bt][3]);
            bfg.u[0] = h01; bfg.u[1] = h23; bfg.u[2] = h01; bfg.u[3] = h23;
            f32x4 da = {0.f,0.f,0.f,0.f};
            da = __builtin_amdgcn_mfma_f32_16x16x32_bf16(S.xA.f, bfg.f, da, 0,0,0);
            const float4 ew = *(const float4*)&sEndw[(64 + bt*16 + lo16)*20 + quad*4];
            float pt = da[0]*ew.x + da[1]*ew.y + da[2]*ew.z + da[3]*ew.w;
            pt += __shfl_xor(pt, 16, 64);
            pt += __shfl_xor(pt, 32, 64);
            if (bt == quad) o1 = pt;
        }
        out[(size_t)S.nr*CM + lane]      = o0 + endb0;
        out[(size_t)S.nr*CM + 64 + lane] = o1 + endb1;
    };

    const int base = (blockIdx.x*4 + wave) * 4;

    PS S; front(base, S);
    #pragma unroll 1
    for (int it = 0; it < 3; it++){
        PS T;
        front(base + it + 1, T);   // loads of point it+1 issue early
        back(S);                   // compute of point it interleaved by scheduler
        S = T;
    }
    back(S);
}

extern "C" void kernel_launch(void* const* d_in, const int* in_sizes, int n_in,
                              void* d_out, int out_size, void* d_ws, size_t ws_size,
                              hipStream_t stream)
{
    const float* p     = (const float*)d_in[0];
    const float* P     = (const float*)d_in[1];
    const float* F     = (const float*)d_in[2];
    const float* gamma = (const float*)d_in[3];
    const float* beta  = (const float*)d_in[4];
    const float* w1    = (const float*)d_in[5];
    const float* b1    = (const float*)d_in[6];
    const float* w2    = (const float*)d_in[7];
    const float* b2    = (const float*)d_in[8];
    const float* midw  = (const float*)d_in[9];
    const float* midb  = (const float*)d_in[10];
    const float* mlpw  = (const float*)d_in[11];
    const float* mlpb  = (const float*)d_in[12];
    const float* endw  = (const float*)d_in[13];
    const float* endb  = (const float*)d_in[14];
    float* ws  = (float*)d_ws;
    float* out = (float*)d_out;

    hipMemsetAsync(d_ws, 0, 32, stream);
    xconv_stats<<<256, 256, 0, stream>>>(p, P, ws);
    xconv_main <<<1024, 256, 0, stream>>>(p, P, F, gamma, beta, w1, b1, w2, b2,
                                          midw, midb, mlpw, mlpb, endw, endb, ws, out);
}

// Round 8
// 146.153 us; speedup vs baseline: 1.0346x; 1.0346x over previous
//
#include <hip/hip_runtime.h>
#include <cstddef>

#define N_TOT   8
#define R_TOT   2048
#define NR_TOT  (N_TOT*R_TOT)      // 16384 points
#define KK      16
#define CL      64
#define CM      128
#define EPSV    1e-5f
#define CNTF    262144.0f

typedef float    f32x4  __attribute__((ext_vector_type(4)));
typedef short    bf16x8 __attribute__((ext_vector_type(8)));
typedef unsigned u32x2  __attribute__((ext_vector_type(2)));
typedef unsigned u32x4  __attribute__((ext_vector_type(4)));

union FragU { bf16x8 f; unsigned u[4]; };

__device__ __forceinline__ float elu_f(float x){
    return x > 0.f ? x : (__expf(x) - 1.f);
}

#if defined(__has_builtin) && __has_builtin(__builtin_amdgcn_cvt_pk_bf16_f32)
__device__ __forceinline__ unsigned pk_bf16(float a, float b){
    auto v = __builtin_amdgcn_cvt_pk_bf16_f32(a, b);   // lo=a, hi=b
    unsigned u; __builtin_memcpy(&u, &v, 4);
    return u;
}
#else
__device__ __forceinline__ unsigned pk_bf16(float a, float b){
    unsigned ua = __float_as_uint(a), ub = __float_as_uint(b);
    ua += 0x7fff + ((ua >> 16) & 1);
    ub += 0x7fff + ((ub >> 16) & 1);
    return (ua >> 16) | (ub & 0xffff0000u);
}
#endif
__device__ __forceinline__ float bf_lo(unsigned u){ return __uint_as_float(u << 16); }
__device__ __forceinline__ float bf_hi(unsigned u){ return __uint_as_float(u & 0xffff0000u); }

__device__ __forceinline__ void split4(const float* x, unsigned* o){
    unsigned h01 = pk_bf16(x[0], x[1]);
    unsigned h23 = pk_bf16(x[2], x[3]);
    float l0 = x[0] - bf_lo(h01), l1 = x[1] - bf_hi(h01);
    float l2 = x[2] - bf_lo(h23), l3 = x[3] - bf_hi(h23);
    o[0] = h01; o[1] = h23; o[2] = pk_bf16(l0, l1); o[3] = pk_bf16(l2, l3);
}

// ---------------- Pass 1: global BN stats ----------------
__global__ __launch_bounds__(256) void xconv_stats(
    const float* __restrict__ p, const float* __restrict__ P, float* __restrict__ ws)
{
    const int g = blockIdx.x*256 + threadIdx.x;        // group of 4 neighbor rows
    const float4* P4 = (const float4*)(P + (size_t)g*12);
    float4 a = P4[0], b = P4[1], c = P4[2];
    const int nr = g >> 2;
    float pp0 = p[nr*3], pp1 = p[nr*3+1], pp2 = p[nr*3+2];
    float vx0=a.x-pp0, vx1=a.w-pp0, vx2=b.z-pp0, vx3=c.y-pp0;
    float vy0=a.y-pp1, vy1=b.x-pp1, vy2=b.w-pp1, vy3=c.z-pp1;
    float vz0=a.z-pp2, vz1=b.y-pp2, vz2=c.x-pp2, vz3=c.w-pp2;
    float s1[3], s2[3];
    s1[0]=vx0+vx1+vx2+vx3; s2[0]=vx0*vx0+vx1*vx1+vx2*vx2+vx3*vx3;
    s1[1]=vy0+vy1+vy2+vy3; s2[1]=vy0*vy0+vy1*vy1+vy2*vy2+vy3*vy3;
    s1[2]=vz0+vz1+vz2+vz3; s2[2]=vz0*vz0+vz1*vz1+vz2*vz2+vz3*vz3;

    #pragma unroll
    for (int off = 32; off > 0; off >>= 1){
        #pragma unroll
        for (int d = 0; d < 3; d++){
            s1[d] += __shfl_down(s1[d], off, 64);
            s2[d] += __shfl_down(s2[d], off, 64);
        }
    }
    __shared__ float red[4][6];
    int wave = threadIdx.x >> 6, lane = threadIdx.x & 63;
    if (lane == 0){
        #pragma unroll
        for (int d = 0; d < 3; d++){ red[wave][d] = s1[d]; red[wave][3+d] = s2[d]; }
    }
    __syncthreads();
    if (threadIdx.x < 6){
        float v = red[0][threadIdx.x] + red[1][threadIdx.x]
                + red[2][threadIdx.x] + red[3][threadIdx.x];
        atomicAdd(&ws[threadIdx.x], v);
    }
}

// ---------------- Pass 2: fused MFMA kernel ----------------
// 1024 blocks x 256 thr; wave = 4 points, single point in flight (R6/R7
// showed source-level pipelining/prefetch is neutral-to-negative here).
// w1/w2 fragments live in LDS (block-staged once): -64 persistent VGPR vs R2
// -> more waves/SIMD for TLP latency hiding. No min-waves launch bound (R4).
__global__ __launch_bounds__(256) void xconv_main(
    const float* __restrict__ p,   const float* __restrict__ P,
    const float* __restrict__ F,
    const float* __restrict__ gamma,const float* __restrict__ beta,
    const float* __restrict__ w1,  const float* __restrict__ b1,
    const float* __restrict__ w2,  const float* __restrict__ b2,
    const float* __restrict__ midw,const float* __restrict__ midb,
    const float* __restrict__ mlpw,const float* __restrict__ mlpb,
    const float* __restrict__ endw,const float* __restrict__ endb,
    const float* __restrict__ ws,  float* __restrict__ out)
{
    __shared__ float    sEndw[128*20];     // 10240 B, rows padded to 80 B
    __shared__ unsigned sW1[2*64*20];      // 10240 B, per-(s,lane) 80 B rows
    __shared__ unsigned sW2[8*64*4];       //  8192 B, per-(b,s,lane) 16 B frags

    const int tid  = threadIdx.x;
    const int lane = tid & 63;
    const int lo16 = lane & 15;
    const int quad = lane >> 4;
    const int wave = tid >> 6;

    // ---- parallel LDS staging: wave0=w1, wave1=w2, waves2-3=endw ----
    if (wave == 0){
        #pragma unroll
        for (int s = 0; s < 2; s++)
            #pragma unroll
            for (int j = 0; j < 8; j++){
                int q = s*32 + quad*8 + j;
                u32x2 v;
                v.x = pk_bf16(w1[q],       w1[64 + q]);   // (w1_0, w1_1)
                v.y = pk_bf16(w1[128 + q], b1[q]);        // (w1_2, bias)
                *(u32x2*)&sW1[(s*64 + lane)*20 + j*2] = v;
            }
    } else if (wave == 1){
        #pragma unroll
        for (int b = 0; b < 4; b++)
            #pragma unroll
            for (int s = 0; s < 2; s++){
                u32x4 f;
                #pragma unroll
                for (int d = 0; d < 4; d++){
                    int q0 = s*32 + quad*8 + d*2;
                    int idx = q0*64 + b*16 + lo16;
                    f[d] = pk_bf16(w2[idx], w2[idx + 64]);
                }
                *(u32x4*)&sW2[((b*2 + s)*64 + lane)*4] = f;
            }
    } else {
        int c = tid - 128;                                // 0..127
        const float4* ep = (const float4*)endw;
        #pragma unroll
        for (int i = 0; i < 4; i++)
            *(float4*)&sEndw[c*20 + i*4] = ep[c*4 + i];
    }

    // ---- per-lane persistent regs (small) ----
    float sc[3], sh[3];
    #pragma unroll
    for (int d = 0; d < 3; d++){
        float mean = ws[d] / CNTF;
        float var  = ws[3+d] / CNTF - mean*mean;
        float s    = gamma[d] * rsqrtf(var + EPSV);
        sc[d] = s; sh[d] = beta[d] - mean*s;
    }
    FragU mlpA[2];
    {
        float mw[4];
        #pragma unroll
        for (int r = 0; r < 4; r++) mw[r] = mlpw[(quad*4 + r)*16 + lo16];
        unsigned o[4]; split4(mw, o);
        mlpA[0].u[0]=o[0]; mlpA[0].u[1]=o[1]; mlpA[0].u[2]=o[0]; mlpA[0].u[3]=o[1];
        mlpA[1].u[0]=o[2]; mlpA[1].u[1]=o[3]; mlpA[1].u[2]=o[2]; mlpA[1].u[3]=o[3];
    }
    float mlpbr[4];
    #pragma unroll
    for (int r = 0; r < 4; r++) mlpbr[r] = mlpb[quad*4 + r];
    float mw0[4], mw1[4], mw2[4], mbv[4];
    #pragma unroll
    for (int j = 0; j < 4; j++){
        int m2 = quad*4 + j;
        mw0[j] = midw[m2]; mw1[j] = midw[16 + m2]; mw2[j] = midw[32 + m2];
        mbv[j] = midb[m2];
    }
    float b2r[4];
    #pragma unroll
    for (int b = 0; b < 4; b++) b2r[b] = b2[b*16 + lo16];
    const float endb0 = endb[lane], endb1 = endb[64 + lane];

    __syncthreads();

    const int wglobal = blockIdx.x*4 + wave;   // 0..4095

    #pragma unroll 1
    for (int it = 0; it < 4; it++){
        const int nr = wglobal*4 + it;

        // ---- global loads up front ----
        float fv[4][4];                        // F[nr][quad*4+r][bt*16+lo16]
        #pragma unroll
        for (int bt = 0; bt < 4; bt++)
            #pragma unroll
            for (int r = 0; r < 4; r++)
                fv[bt][r] = F[(size_t)nr*1024 + (quad*4 + r)*64 + bt*16 + lo16];
        const int pb = nr*48 + lo16*3;
        float P0 = P[pb], P1 = P[pb+1], P2 = P[pb+2];
        float pp0 = p[nr*3], pp1 = p[nr*3+1], pp2 = p[nr*3+2];

        const float pn0 = (P0 - pp0)*sc[0] + sh[0];
        const float pn1 = (P1 - pp1)*sc[1] + sh[1];
        const float pn2 = (P2 - pp2)*sc[2] + sh[2];

        // ---- h1 = elu(Pn @ w1 + b1) -> A-frags, weights from LDS ----
        FragU hf[2];
        #pragma unroll
        for (int s = 0; s < 2; s++){
            const u32x4* wp = (const u32x4*)&sW1[(s*64 + lane)*20];
            #pragma unroll
            for (int d = 0; d < 4; d++){
                u32x4 w = wp[d];              // pa(2d), pb(2d), pa(2d+1), pb(2d+1)
                float h0 = bf_hi(w.y);
                h0 = fmaf(pn0, bf_lo(w.x), h0);
                h0 = fmaf(pn1, bf_hi(w.x), h0);
                h0 = fmaf(pn2, bf_lo(w.y), h0);
                float h1v = bf_hi(w.w);
                h1v = fmaf(pn0, bf_lo(w.z), h1v);
                h1v = fmaf(pn1, bf_hi(w.z), h1v);
                h1v = fmaf(pn2, bf_lo(w.w), h1v);
                hf[s].u[d] = pk_bf16(elu_f(h0), elu_f(h1v));
            }
        }

        // ---- X0 (exact fp32) -> split B-frag ----
        float x0[4];
        #pragma unroll
        for (int j = 0; j < 4; j++)
            x0[j] = fmaf(pn2, mw2[j], fmaf(pn1, mw1[j], fmaf(pn0, mw0[j], mbv[j])));
        FragU x0f; split4(x0, x0f.u);

        // ---- mlp: X^T = mlpw^T @ X0^T (exact), ELU, split -> agg A-frag ----
        f32x4 dx = {0.f,0.f,0.f,0.f};
        dx = __builtin_amdgcn_mfma_f32_16x16x32_bf16(mlpA[0].f, x0f.f, dx, 0,0,0);
        dx = __builtin_amdgcn_mfma_f32_16x16x32_bf16(mlpA[1].f, x0f.f, dx, 0,0,0);
        float xv[4];
        #pragma unroll
        for (int r = 0; r < 4; r++) xv[r] = elu_f(dx[r] + mlpbr[r]);
        FragU xA; split4(xv, xA.u);

        float o0 = 0.f, o1 = 0.f;

        // ---- tiles 0..3: lift2 (MFMA) -> ELU -> hi-dup B-frag -> agg ----
        #pragma unroll
        for (int b = 0; b < 4; b++){
            FragU wf0, wf1;
            *(u32x4*)wf0.u = *(const u32x4*)&sW2[((b*2 + 0)*64 + lane)*4];
            *(u32x4*)wf1.u = *(const u32x4*)&sW2[((b*2 + 1)*64 + lane)*4];
            f32x4 dl = {0.f,0.f,0.f,0.f};
            dl = __builtin_amdgcn_mfma_f32_16x16x32_bf16(hf[0].f, wf0.f, dl, 0,0,0);
            dl = __builtin_amdgcn_mfma_f32_16x16x32_bf16(hf[1].f, wf1.f, dl, 0,0,0);
            float fl[4];
            #pragma unroll
            for (int r = 0; r < 4; r++) fl[r] = elu_f(dl[r] + b2r[b]);
            FragU bfg;
            unsigned h01 = pk_bf16(fl[0], fl[1]), h23 = pk_bf16(fl[2], fl[3]);
            bfg.u[0] = h01; bfg.u[1] = h23; bfg.u[2] = h01; bfg.u[3] = h23;
            f32x4 da = {0.f,0.f,0.f,0.f};
            da = __builtin_amdgcn_mfma_f32_16x16x32_bf16(xA.f, bfg.f, da, 0,0,0);
            const float4 ew = *(const float4*)&sEndw[(b*16 + lo16)*20 + quad*4];
            float pt = da[0]*ew.x + da[1]*ew.y + da[2]*ew.z + da[3]*ew.w;
            pt += __shfl_xor(pt, 16, 64);
            pt += __shfl_xor(pt, 32, 64);
            if (b == quad) o0 = pt;            // c = b*16+lo16 == lane
        }
        // ---- tiles 4..7: raw F -> hi-dup B-frag -> agg ----
        #pragma unroll
        for (int bt = 0; bt < 4; bt++){
            FragU bfg;
            unsigned h01 = pk_bf16(fv[bt][0], fv[bt][1]);
            unsigned h23 = pk_bf16(fv[bt][2], fv[bt][3]);
            bfg.u[0] = h01; bfg.u[1] = h23; bfg.u[2] = h01; bfg.u[3] = h23;
            f32x4 da = {0.f,0.f,0.f,0.f};
            da = __builtin_amdgcn_mfma_f32_16x16x32_bf16(xA.f, bfg.f, da, 0,0,0);
            const float4 ew = *(const float4*)&sEndw[(64 + bt*16 + lo16)*20 + quad*4];
            float pt = da[0]*ew.x + da[1]*ew.y + da[2]*ew.z + da[3]*ew.w;
            pt += __shfl_xor(pt, 16, 64);
            pt += __shfl_xor(pt, 32, 64);
            if (bt == quad) o1 = pt;           // c = 64 + bt*16+lo16 == 64+lane
        }

        out[(size_t)nr*CM + lane]      = o0 + endb0;
        out[(size_t)nr*CM + 64 + lane] = o1 + endb1;
    }
}

extern "C" void kernel_launch(void* const* d_in, const int* in_sizes, int n_in,
                              void* d_out, int out_size, void* d_ws, size_t ws_size,
                              hipStream_t stream)
{
    const float* p     = (const float*)d_in[0];
    const float* P     = (const float*)d_in[1];
    const float* F     = (const float*)d_in[2];
    const float* gamma = (const float*)d_in[3];
    const float* beta  = (const float*)d_in[4];
    const float* w1    = (const float*)d_in[5];
    const float* b1    = (const float*)d_in[6];
    const float* w2    = (const float*)d_in[7];
    const float* b2    = (const float*)d_in[8];
    const float* midw  = (const float*)d_in[9];
    const float* midb  = (const float*)d_in[10];
    const float* mlpw  = (const float*)d_in[11];
    const float* mlpb  = (const float*)d_in[12];
    const float* endw  = (const float*)d_in[13];
    const float* endb  = (const float*)d_in[14];
    float* ws  = (float*)d_ws;
    float* out = (float*)d_out;

    hipMemsetAsync(d_ws, 0, 32, stream);
    xconv_stats<<<256, 256, 0, stream>>>(p, P, ws);
    xconv_main <<<1024, 256, 0, stream>>>(p, P, F, gamma, beta, w1, b1, w2, b2,
                                          midw, midb, mlpw, mlpb, endw, endb, ws, out);
}